// Round 11
// baseline (742.533 us; speedup 1.0000x reference)
//
#include <hip/hip_runtime.h>
#include <math.h>

#define D_TOT 480

typedef short bf16x8 __attribute__((ext_vector_type(8)));
typedef float f32x4 __attribute__((ext_vector_type(4)));

#define MFMA16(a, b, c) __builtin_amdgcn_mfma_f32_16x16x32_bf16((a), (b), (c), 0, 0, 0)

static __device__ __forceinline__ unsigned short f2bf(float x) {
  unsigned u = __float_as_uint(x);
  u += 0x7FFFu + ((u >> 16) & 1u);   // RNE (inputs finite)
  return (unsigned short)(u >> 16);
}

// ---------------------------------------------------------------------------
// K0 (templated impl): fused precompute + pack, one 32-k-row strip per block.
//   M_b = (Wq . Wd . Wk^T) * scale, scale folds all e3nn norms.
//   Pack B = [M_b | Wv/sqrt(M)] bf16 fragments (1 KB each):
//   elem (l,j) of frag (ct*ktn+kt) = B[k=kt*32+(l>>4)*8+j][c=ct*16+(l&15)].
// LDS: sWkT = Wk transposed, (M+1) padded; sT = 32xM strip (reused for Ms).
// ---------------------------------------------------------------------------
template <int M, int DEG, int BASE>
static __device__ void precompute_impl(
    const float* __restrict__ Wq, const float* __restrict__ Wk,
    const float* __restrict__ Wd, const float* __restrict__ Wv,
    unsigned short* __restrict__ Bp, int kt, float* lds) {
  float* sWkT = lds;                 // M*(M+1)
  float* sT   = lds + M * (M + 1);   // 32*M

  constexpr int TPR = 256 / M;       // thread-rows per pass
  constexpr int RPT = 32 / TPR;      // rows per thread
  constexpr int nct = M / 8;
  constexpr int ktn = M / 32;

  int t = threadIdx.x;
  float scale = 1.0f / ((float)M * (float)M * sqrtf(1440.0f * (float)DEG));
  float sm = rsqrtf((float)M);

  // stage Wk transposed (padded): coalesced read, conflict-free write
  for (int i = t; i < M * M; i += 256) {
    int r = i / M, c = i - r * M;
    sWkT[c * (M + 1) + r] = Wk[i];
  }

  // T = Wq[strip] . Wd  (32 x M), direct from global (coalesced Wd)
  {
    int c = t % M, r0 = t / M;
    float acc[RPT];
#pragma unroll
    for (int rr = 0; rr < RPT; ++rr) acc[rr] = 0.f;
#pragma unroll 4
    for (int a = 0; a < M; ++a) {
      float wd = Wd[a * M + c];
#pragma unroll
      for (int rr = 0; rr < RPT; ++rr)
        acc[rr] += Wq[(kt * 32 + r0 + rr * TPR) * M + a] * wd;
    }
    __syncthreads();   // sWkT staged; also order sT writes
#pragma unroll
    for (int rr = 0; rr < RPT; ++rr) sT[(r0 + rr * TPR) * M + c] = acc[rr];
  }
  __syncthreads();

  // Ms = T . Wk^T * scale  (32 x M), from LDS (stride-1 sWkT, broadcast sT)
  {
    int j = t % M, r0 = t / M;
    float acc[RPT];
#pragma unroll
    for (int rr = 0; rr < RPT; ++rr) acc[rr] = 0.f;
#pragma unroll 4
    for (int c = 0; c < M; ++c) {
      float wk = sWkT[c * (M + 1) + j];
#pragma unroll
      for (int rr = 0; rr < RPT; ++rr)
        acc[rr] += sT[(r0 + rr * TPR) * M + c] * wk;
    }
    __syncthreads();   // everyone done reading sT
#pragma unroll
    for (int rr = 0; rr < RPT; ++rr) sT[(r0 + rr * TPR) * M + j] = acc[rr] * scale;
  }
  __syncthreads();

  // pack this strip's fragments (M-half from sT, Wv-half from global)
  for (int idx = t; idx < nct * 512; idx += 256) {
    int ct = idx >> 9, rem = idx & 511, l = rem >> 3, j = rem & 7;
    int kl = (l >> 4) * 8 + j;
    int c = ct * 16 + (l & 15);
    float val = (c < M) ? sT[kl * M + c] : Wv[(kt * 32 + kl) * M + (c - M)] * sm;
    Bp[BASE + (ct * ktn + kt) * 512 + rem] = f2bf(val);
  }
}

// single launch, 7 blocks: 4 strips of irrep0, 2 of irrep1, 1 of irrep2
__global__ __launch_bounds__(256) void precompute_all(
    const float* __restrict__ Wq0, const float* __restrict__ Wq1, const float* __restrict__ Wq2,
    const float* __restrict__ Wk0, const float* __restrict__ Wk1, const float* __restrict__ Wk2,
    const float* __restrict__ Wd0, const float* __restrict__ Wd1, const float* __restrict__ Wd2,
    const float* __restrict__ Wv0, const float* __restrict__ Wv1, const float* __restrict__ Wv2,
    unsigned short* __restrict__ Bp) {
  extern __shared__ float lds[];
  int b = blockIdx.x;
  if (b < 4)      precompute_impl<128, 1, 0>(Wq0, Wk0, Wd0, Wv0, Bp, b, lds);
  else if (b < 6) precompute_impl<64, 3, 32768>(Wq1, Wk1, Wd1, Wv1, Bp, b - 4, lds);
  else            precompute_impl<32, 5, 40960>(Wq2, Wk2, Wd2, Wv2, Bp, 0, lds);
}

// ---------------------------------------------------------------------------
// Fused stationary-B kernel (R9/R10 verbatim, occupancy raised to 4 blk/CU).
// Block = 4 waves sharing each 16-node tile; block owns a CONTIGUOUS range
// of tiles (register accumulation held across tiles, flush on graph change).
// Wave w owns column slice: irrep0 ct {2w,2w+1}; irrep1 ct {w}; irrep2 (w>=2).
// B-fragments live in REGISTERS for the whole kernel.  A-fragments + logit
// x read straight from global (L1).  Cross-wave logit sum via 16-float LDS
// atomics, 3-buffer rotation, ONE barrier per tile.
// ---------------------------------------------------------------------------
__global__ __launch_bounds__(256, 4) void fused_stat_kernel(
    const float* __restrict__ f, const unsigned short* __restrict__ Bpack,
    const int* __restrict__ batch,
    float* __restrict__ outnum, float* __restrict__ norm,
    int N, int tpb, int ntiles) {
  __shared__ float lds_logit[3][16];
  int t = threadIdx.x, w = t >> 6, lane = t & 63;
  int q = lane >> 4, lm = lane & 15;

  if (t < 48) ((float*)lds_logit)[t] = 0.f;
  __syncthreads();

  int t0 = blockIdx.x * tpb;
  int t1 = min(t0 + tpb, ntiles);
  if (t0 >= t1) return;   // block-uniform

  const bf16x8* B0f = (const bf16x8*)Bpack;
  const bf16x8* B1f = (const bf16x8*)(Bpack + 32768);
  const bf16x8* B2f = (const bf16x8*)(Bpack + 40960);

  // ---- stationary B fragments (registers, loaded once) ----
  bf16x8 Bu0[2][4], Bv0[2][4], Bu1[2], Bv1[2], Bu2, Bv2;
#pragma unroll
  for (int ctl = 0; ctl < 2; ++ctl)
#pragma unroll
    for (int k = 0; k < 4; ++k) {
      Bu0[ctl][k] = B0f[((2 * w + ctl) * 4 + k) * 64 + lane];
      Bv0[ctl][k] = B0f[((2 * w + ctl + 8) * 4 + k) * 64 + lane];
    }
#pragma unroll
  for (int k = 0; k < 2; ++k) {
    Bu1[k] = B1f[(w * 2 + k) * 64 + lane];
    Bv1[k] = B1f[((w + 4) * 2 + k) * 64 + lane];
  }
  bool has2 = (w >= 2);
  int ct2 = has2 ? (w - 2) : 0;
  Bu2 = B2f[ct2 * 64 + lane];
  Bv2 = B2f[(ct2 + 2) * 64 + lane];

  // ---- cross-tile accumulators ----
  float racc0[2] = {0.f, 0.f};
  float racc1[3] = {0.f, 0.f, 0.f};
  float racc2[5] = {0.f, 0.f, 0.f, 0.f, 0.f};
  float naccw = 0.f;
  int cur_g = -1;

  auto wavered = [&](float s) -> float {
    s += __shfl_xor(s, 16);
    s += __shfl_xor(s, 32);
    return s;
  };
  auto flushf = [&](int g) {
    float* og = outnum + (size_t)g * 480;
#pragma unroll
    for (int ctl = 0; ctl < 2; ++ctl) {
      float s = wavered(racc0[ctl]);
      if (lane < 16) atomicAdd(og + (2 * w + ctl) * 16 + lane, s);
      racc0[ctl] = 0.f;
    }
#pragma unroll
    for (int d = 0; d < 3; ++d) {
      float s = wavered(racc1[d]);
      if (lane < 16) atomicAdd(og + 128 + 3 * (w * 16 + lane) + d, s);
      racc1[d] = 0.f;
    }
    if (has2) {
#pragma unroll
      for (int d = 0; d < 5; ++d) {
        float s = wavered(racc2[d]);
        if (lane < 16) atomicAdd(og + 320 + 5 * (ct2 * 16 + lane) + d, s);
        racc2[d] = 0.f;
      }
    }
    if (w == 0) {
      float s = wavered(naccw);
      if (lane == 0) atomicAdd(norm + g, s);
      naccw = 0.f;
    }
  };

  for (int ti = t0; ti < t1; ++ti) {
    int p = ti % 3;
    int nt = ti * 16;
    int valid = min(16, N - nt);

    // ---- A-fragments from global windows (row = lm, k-chunk = q) ----
    long rr = nt + (lm < valid ? lm : valid - 1);
    const float4* fr4 = reinterpret_cast<const float4*>(f + rr * 480);
    bf16x8 a0[4], a1[3][2], a2[5];
#pragma unroll
    for (int ks = 0; ks < 4; ++ks) {
      float4 A = fr4[ks * 8 + 2 * q];
      float4 B = fr4[ks * 8 + 2 * q + 1];
      bf16x8 v;
      v[0] = (short)f2bf(A.x); v[1] = (short)f2bf(A.y);
      v[2] = (short)f2bf(A.z); v[3] = (short)f2bf(A.w);
      v[4] = (short)f2bf(B.x); v[5] = (short)f2bf(B.y);
      v[6] = (short)f2bf(B.z); v[7] = (short)f2bf(B.w);
      a0[ks] = v;
    }
#pragma unroll
    for (int h = 0; h < 2; ++h) {
      unsigned short bb[24];
#pragma unroll
      for (int i = 0; i < 6; ++i) {
        float4 x4 = fr4[32 + 24 * h + 6 * q + i];
        bb[i * 4 + 0] = f2bf(x4.x); bb[i * 4 + 1] = f2bf(x4.y);
        bb[i * 4 + 2] = f2bf(x4.z); bb[i * 4 + 3] = f2bf(x4.w);
      }
#pragma unroll
      for (int d = 0; d < 3; ++d) {
        bf16x8 v;
#pragma unroll
        for (int j = 0; j < 8; ++j) v[j] = (short)bb[3 * j + d];
        a1[d][h] = v;
      }
    }
    {
      unsigned short bb[40];
#pragma unroll
      for (int i = 0; i < 10; ++i) {
        float4 x4 = fr4[80 + 10 * q + i];
        bb[i * 4 + 0] = f2bf(x4.x); bb[i * 4 + 1] = f2bf(x4.y);
        bb[i * 4 + 2] = f2bf(x4.z); bb[i * 4 + 3] = f2bf(x4.w);
      }
#pragma unroll
      for (int d = 0; d < 5; ++d) {
        bf16x8 v;
#pragma unroll
        for (int j = 0; j < 8; ++j) v[j] = (short)bb[5 * j + d];
        a2[d] = v;
      }
    }

    // x for logit dot, straight from global (L1 hit), clamped for tails
    auto xg = [&](int r, int c) -> float {
      int nn = nt + q * 4 + r;
      if (nn >= N) nn = N - 1;
      return f[(size_t)nn * 480 + c];
    };

    // ---- u-phase (slice) + dot, interleaved per irrep ----
    float pl[4] = {0.f, 0.f, 0.f, 0.f};
#pragma unroll
    for (int ctl = 0; ctl < 2; ++ctl) {
      f32x4 u = {0.f, 0.f, 0.f, 0.f};
      u = MFMA16(a0[0], Bu0[ctl][0], u);
      u = MFMA16(a0[1], Bu0[ctl][1], u);
      u = MFMA16(a0[2], Bu0[ctl][2], u);
      u = MFMA16(a0[3], Bu0[ctl][3], u);
      int c = (2 * w + ctl) * 16 + lm;
#pragma unroll
      for (int r = 0; r < 4; ++r) pl[r] += u[r] * xg(r, c);
    }
#pragma unroll
    for (int d = 0; d < 3; ++d) {
      f32x4 u = {0.f, 0.f, 0.f, 0.f};
      u = MFMA16(a1[d][0], Bu1[0], u);
      u = MFMA16(a1[d][1], Bu1[1], u);
      int c = 128 + 3 * (w * 16 + lm) + d;
#pragma unroll
      for (int r = 0; r < 4; ++r) pl[r] += u[r] * xg(r, c);
    }
    if (has2) {
#pragma unroll
      for (int d = 0; d < 5; ++d) {
        f32x4 u = {0.f, 0.f, 0.f, 0.f};
        u = MFMA16(a2[d], Bu2, u);
        int c = 320 + 5 * (ct2 * 16 + lm) + d;
#pragma unroll
        for (int r = 0; r < 4; ++r) pl[r] += u[r] * xg(r, c);
      }
    }
    // reduce slice partials across the 16-lane group, add to shared logits
#pragma unroll
    for (int off = 1; off < 16; off <<= 1) {
#pragma unroll
      for (int r = 0; r < 4; ++r) pl[r] += __shfl_xor(pl[r], off);
    }
    if (lm == 0) {
#pragma unroll
      for (int r = 0; r < 4; ++r) atomicAdd(&lds_logit[p][q * 4 + r], pl[r]);
    }
    __syncthreads();

    float wgt[4];
#pragma unroll
    for (int r = 0; r < 4; ++r) {
      int node = q * 4 + r;
      wgt[r] = (node < valid) ? __expf(lds_logit[p][node]) : 0.f;
    }
    // rotate: zero the buffer tile ti+2 will use (3-buffer schedule, race-free)
    if (t < 16) lds_logit[(ti + 2) % 3][t] = 0.f;

    // ---- segmented v accumulation over sorted batch ----
    {
      int nn = nt + (lm < valid ? lm : valid - 1);
      if (nn >= N) nn = N - 1;
      int gl = batch[nn];
      int gp = __shfl(gl, (lane == 0) ? 0 : lane - 1);
      unsigned long long bm = __ballot(lm > 0 && lm < valid && gl != gp);
      unsigned segm = (unsigned)bm & 0xFFFEu;

      int a = 0;
      while (a < valid) {
        unsigned hi = segm & ~((1u << (a + 1)) - 1u);
        int b = hi ? (int)__builtin_ctz(hi) : valid;
        int gs = __shfl(gl, a);
        if (gs != cur_g) {
          if (cur_g >= 0) flushf(cur_g);
          cur_g = gs;
        }
        int nq = q * 4;
        float m0 = (nq + 0 >= a && nq + 0 < b) ? wgt[0] : 0.f;
        float m1 = (nq + 1 >= a && nq + 1 < b) ? wgt[1] : 0.f;
        float m2 = (nq + 2 >= a && nq + 2 < b) ? wgt[2] : 0.f;
        float m3 = (nq + 3 >= a && nq + 3 < b) ? wgt[3] : 0.f;
        if (w == 0 && lm == 0) naccw += m0 + m1 + m2 + m3;
#pragma unroll
        for (int ctl = 0; ctl < 2; ++ctl) {
          f32x4 v = {0.f, 0.f, 0.f, 0.f};
          v = MFMA16(a0[0], Bv0[ctl][0], v);
          v = MFMA16(a0[1], Bv0[ctl][1], v);
          v = MFMA16(a0[2], Bv0[ctl][2], v);
          v = MFMA16(a0[3], Bv0[ctl][3], v);
          racc0[ctl] += m0 * v[0] + m1 * v[1] + m2 * v[2] + m3 * v[3];
        }
#pragma unroll
        for (int d = 0; d < 3; ++d) {
          f32x4 v = {0.f, 0.f, 0.f, 0.f};
          v = MFMA16(a1[d][0], Bv1[0], v);
          v = MFMA16(a1[d][1], Bv1[1], v);
          racc1[d] += m0 * v[0] + m1 * v[1] + m2 * v[2] + m3 * v[3];
        }
        if (has2) {
#pragma unroll
          for (int d = 0; d < 5; ++d) {
            f32x4 v = {0.f, 0.f, 0.f, 0.f};
            v = MFMA16(a2[d], Bv2, v);
            racc2[d] += m0 * v[0] + m1 * v[1] + m2 * v[2] + m3 * v[3];
          }
        }
        a = b;
      }
    }
  }
  if (cur_g >= 0) flushf(cur_g);
}

// ---------------------------------------------------------------------------
// finalize: out = num / max(norm, 1e-8)
// ---------------------------------------------------------------------------
__global__ __launch_bounds__(256) void finalize_kernel(
    float* __restrict__ out, const float* __restrict__ norm, int total) {
  int idx = blockIdx.x * blockDim.x + threadIdx.x;
  if (idx < total) {
    int g = idx / 480;
    out[idx] = out[idx] / fmaxf(norm[g], 1e-8f);
  }
}

extern "C" void kernel_launch(void* const* d_in, const int* in_sizes, int n_in,
                              void* d_out, int out_size, void* d_ws, size_t ws_size,
                              hipStream_t stream) {
  const float* f   = (const float*)d_in[0];
  const int* batch = (const int*)d_in[13];

  int N = in_sizes[0] / D_TOT;
  int G = out_size / D_TOT;

  // ws bytes: [0, 86016) Bpack bf16 (43008); [86016, ...) norm
  unsigned short* Bpack = (unsigned short*)d_ws;
  float* norm = (float*)((char*)d_ws + 86016);
  float* out  = (float*)d_out;

  hipMemsetAsync(d_out, 0, (size_t)out_size * sizeof(float), stream);
  hipMemsetAsync(norm, 0, (size_t)G * sizeof(float), stream);

  // one launch, 7 blocks; LDS sized for the M=128 instance (opt-in > 64 KB)
  int lds128 = (128 * 129 + 32 * 128) * 4;   // 82432
  hipFuncSetAttribute((const void*)precompute_all,
                      hipFuncAttributeMaxDynamicSharedMemorySize, lds128);
  precompute_all<<<7, 256, lds128, stream>>>(
      (const float*)d_in[1], (const float*)d_in[2], (const float*)d_in[3],
      (const float*)d_in[4], (const float*)d_in[5], (const float*)d_in[6],
      (const float*)d_in[10], (const float*)d_in[11], (const float*)d_in[12],
      (const float*)d_in[7], (const float*)d_in[8], (const float*)d_in[9],
      Bpack);

  int ntiles = (N + 15) / 16;
  int nblocks = 1024;                      // 4 blocks/CU, contiguous tile ranges
  if (nblocks > ntiles) nblocks = ntiles;
  int tpb = (ntiles + nblocks - 1) / nblocks;

  fused_stat_kernel<<<nblocks, 256, 0, stream>>>(
      f, Bpack, batch, out, norm, N, tpb, ntiles);

  finalize_kernel<<<(G * D_TOT + 255) / 256, 256, 0, stream>>>(out, norm, G * D_TOT);
}

// Round 12
// 309.674 us; speedup vs baseline: 2.3978x; 2.3978x over previous
//
#include <hip/hip_runtime.h>
#include <math.h>

#define D_TOT 480

typedef short bf16x8 __attribute__((ext_vector_type(8)));
typedef float f32x4 __attribute__((ext_vector_type(4)));

#define MFMA16(a, b, c) __builtin_amdgcn_mfma_f32_16x16x32_bf16((a), (b), (c), 0, 0, 0)

static __device__ __forceinline__ unsigned short f2bf(float x) {
  unsigned u = __float_as_uint(x);
  u += 0x7FFFu + ((u >> 16) & 1u);   // RNE (inputs finite)
  return (unsigned short)(u >> 16);
}

// ---------------------------------------------------------------------------
// K0 (templated impl): fused precompute + pack, one 32-k-row strip per block.
//   M_b = (Wq . Wd . Wk^T) * scale, scale folds all e3nn norms.
//   Pack B = [M_b | Wv/sqrt(M)] bf16 fragments (1 KB each):
//   elem (l,j) of frag (ct*ktn+kt) = B[k=kt*32+(l>>4)*8+j][c=ct*16+(l&15)].
// LDS: sWkT = Wk transposed, (M+1) padded; sT = 32xM strip (reused for Ms).
// ---------------------------------------------------------------------------
template <int M, int DEG, int BASE>
static __device__ void precompute_impl(
    const float* __restrict__ Wq, const float* __restrict__ Wk,
    const float* __restrict__ Wd, const float* __restrict__ Wv,
    unsigned short* __restrict__ Bp, int kt, float* lds) {
  float* sWkT = lds;                 // M*(M+1)
  float* sT   = lds + M * (M + 1);   // 32*M

  constexpr int TPR = 256 / M;       // thread-rows per pass
  constexpr int RPT = 32 / TPR;      // rows per thread
  constexpr int nct = M / 8;
  constexpr int ktn = M / 32;

  int t = threadIdx.x;
  float scale = 1.0f / ((float)M * (float)M * sqrtf(1440.0f * (float)DEG));
  float sm = rsqrtf((float)M);

  // stage Wk transposed (padded): coalesced read, conflict-free write
  for (int i = t; i < M * M; i += 256) {
    int r = i / M, c = i - r * M;
    sWkT[c * (M + 1) + r] = Wk[i];
  }

  // T = Wq[strip] . Wd  (32 x M), direct from global (coalesced Wd)
  {
    int c = t % M, r0 = t / M;
    float acc[RPT];
#pragma unroll
    for (int rr = 0; rr < RPT; ++rr) acc[rr] = 0.f;
#pragma unroll 4
    for (int a = 0; a < M; ++a) {
      float wd = Wd[a * M + c];
#pragma unroll
      for (int rr = 0; rr < RPT; ++rr)
        acc[rr] += Wq[(kt * 32 + r0 + rr * TPR) * M + a] * wd;
    }
    __syncthreads();   // sWkT staged; also order sT writes
#pragma unroll
    for (int rr = 0; rr < RPT; ++rr) sT[(r0 + rr * TPR) * M + c] = acc[rr];
  }
  __syncthreads();

  // Ms = T . Wk^T * scale  (32 x M), from LDS (stride-1 sWkT, broadcast sT)
  {
    int j = t % M, r0 = t / M;
    float acc[RPT];
#pragma unroll
    for (int rr = 0; rr < RPT; ++rr) acc[rr] = 0.f;
#pragma unroll 4
    for (int c = 0; c < M; ++c) {
      float wk = sWkT[c * (M + 1) + j];
#pragma unroll
      for (int rr = 0; rr < RPT; ++rr)
        acc[rr] += sT[(r0 + rr * TPR) * M + c] * wk;
    }
    __syncthreads();   // everyone done reading sT
#pragma unroll
    for (int rr = 0; rr < RPT; ++rr) sT[(r0 + rr * TPR) * M + j] = acc[rr] * scale;
  }
  __syncthreads();

  // pack this strip's fragments (M-half from sT, Wv-half from global)
  for (int idx = t; idx < nct * 512; idx += 256) {
    int ct = idx >> 9, rem = idx & 511, l = rem >> 3, j = rem & 7;
    int kl = (l >> 4) * 8 + j;
    int c = ct * 16 + (l & 15);
    float val = (c < M) ? sT[kl * M + c] : Wv[(kt * 32 + kl) * M + (c - M)] * sm;
    Bp[BASE + (ct * ktn + kt) * 512 + rem] = f2bf(val);
  }
}

// single launch, 7 blocks: 4 strips of irrep0, 2 of irrep1, 1 of irrep2
__global__ __launch_bounds__(256) void precompute_all(
    const float* __restrict__ Wq0, const float* __restrict__ Wq1, const float* __restrict__ Wq2,
    const float* __restrict__ Wk0, const float* __restrict__ Wk1, const float* __restrict__ Wk2,
    const float* __restrict__ Wd0, const float* __restrict__ Wd1, const float* __restrict__ Wd2,
    const float* __restrict__ Wv0, const float* __restrict__ Wv1, const float* __restrict__ Wv2,
    unsigned short* __restrict__ Bp) {
  extern __shared__ float lds[];
  int b = blockIdx.x;
  if (b < 4)      precompute_impl<128, 1, 0>(Wq0, Wk0, Wd0, Wv0, Bp, b, lds);
  else if (b < 6) precompute_impl<64, 3, 32768>(Wq1, Wk1, Wd1, Wv1, Bp, b - 4, lds);
  else            precompute_impl<32, 5, 40960>(Wq2, Wk2, Wd2, Wv2, Bp, 0, lds);
}

// ---------------------------------------------------------------------------
// Fused stationary-B kernel (R10 verbatim; launch_bounds (256,2) => VGPR 128,
// which HW runs at 4 waves/SIMD — grid raised to 1024 blocks = 4 blocks/CU).
// Block = 4 waves sharing each 16-node tile; block owns a CONTIGUOUS range
// of tiles (register accumulation held across tiles, flush on graph change).
// Wave w owns column slice: irrep0 ct {2w,2w+1}; irrep1 ct {w}; irrep2 (w>=2).
// B-fragments live in REGISTERS for the whole kernel.  A-fragments + logit
// x read straight from global (L1).  Cross-wave logit sum via 16-float LDS
// atomics, 3-buffer rotation, ONE barrier per tile.
// ---------------------------------------------------------------------------
__global__ __launch_bounds__(256, 2) void fused_stat_kernel(
    const float* __restrict__ f, const unsigned short* __restrict__ Bpack,
    const int* __restrict__ batch,
    float* __restrict__ outnum, float* __restrict__ norm,
    int N, int tpb, int ntiles) {
  __shared__ float lds_logit[3][16];
  int t = threadIdx.x, w = t >> 6, lane = t & 63;
  int q = lane >> 4, lm = lane & 15;

  if (t < 48) ((float*)lds_logit)[t] = 0.f;
  __syncthreads();

  int t0 = blockIdx.x * tpb;
  int t1 = min(t0 + tpb, ntiles);
  if (t0 >= t1) return;   // block-uniform

  const bf16x8* B0f = (const bf16x8*)Bpack;
  const bf16x8* B1f = (const bf16x8*)(Bpack + 32768);
  const bf16x8* B2f = (const bf16x8*)(Bpack + 40960);

  // ---- stationary B fragments (registers, loaded once) ----
  bf16x8 Bu0[2][4], Bv0[2][4], Bu1[2], Bv1[2], Bu2, Bv2;
#pragma unroll
  for (int ctl = 0; ctl < 2; ++ctl)
#pragma unroll
    for (int k = 0; k < 4; ++k) {
      Bu0[ctl][k] = B0f[((2 * w + ctl) * 4 + k) * 64 + lane];
      Bv0[ctl][k] = B0f[((2 * w + ctl + 8) * 4 + k) * 64 + lane];
    }
#pragma unroll
  for (int k = 0; k < 2; ++k) {
    Bu1[k] = B1f[(w * 2 + k) * 64 + lane];
    Bv1[k] = B1f[((w + 4) * 2 + k) * 64 + lane];
  }
  bool has2 = (w >= 2);
  int ct2 = has2 ? (w - 2) : 0;
  Bu2 = B2f[ct2 * 64 + lane];
  Bv2 = B2f[(ct2 + 2) * 64 + lane];

  // ---- cross-tile accumulators ----
  float racc0[2] = {0.f, 0.f};
  float racc1[3] = {0.f, 0.f, 0.f};
  float racc2[5] = {0.f, 0.f, 0.f, 0.f, 0.f};
  float naccw = 0.f;
  int cur_g = -1;

  auto wavered = [&](float s) -> float {
    s += __shfl_xor(s, 16);
    s += __shfl_xor(s, 32);
    return s;
  };
  auto flushf = [&](int g) {
    float* og = outnum + (size_t)g * 480;
#pragma unroll
    for (int ctl = 0; ctl < 2; ++ctl) {
      float s = wavered(racc0[ctl]);
      if (lane < 16) atomicAdd(og + (2 * w + ctl) * 16 + lane, s);
      racc0[ctl] = 0.f;
    }
#pragma unroll
    for (int d = 0; d < 3; ++d) {
      float s = wavered(racc1[d]);
      if (lane < 16) atomicAdd(og + 128 + 3 * (w * 16 + lane) + d, s);
      racc1[d] = 0.f;
    }
    if (has2) {
#pragma unroll
      for (int d = 0; d < 5; ++d) {
        float s = wavered(racc2[d]);
        if (lane < 16) atomicAdd(og + 320 + 5 * (ct2 * 16 + lane) + d, s);
        racc2[d] = 0.f;
      }
    }
    if (w == 0) {
      float s = wavered(naccw);
      if (lane == 0) atomicAdd(norm + g, s);
      naccw = 0.f;
    }
  };

  for (int ti = t0; ti < t1; ++ti) {
    int p = ti % 3;
    int nt = ti * 16;
    int valid = min(16, N - nt);

    // ---- A-fragments from global windows (row = lm, k-chunk = q) ----
    long rr = nt + (lm < valid ? lm : valid - 1);
    const float4* fr4 = reinterpret_cast<const float4*>(f + rr * 480);
    bf16x8 a0[4], a1[3][2], a2[5];
#pragma unroll
    for (int ks = 0; ks < 4; ++ks) {
      float4 A = fr4[ks * 8 + 2 * q];
      float4 B = fr4[ks * 8 + 2 * q + 1];
      bf16x8 v;
      v[0] = (short)f2bf(A.x); v[1] = (short)f2bf(A.y);
      v[2] = (short)f2bf(A.z); v[3] = (short)f2bf(A.w);
      v[4] = (short)f2bf(B.x); v[5] = (short)f2bf(B.y);
      v[6] = (short)f2bf(B.z); v[7] = (short)f2bf(B.w);
      a0[ks] = v;
    }
#pragma unroll
    for (int h = 0; h < 2; ++h) {
      unsigned short bb[24];
#pragma unroll
      for (int i = 0; i < 6; ++i) {
        float4 x4 = fr4[32 + 24 * h + 6 * q + i];
        bb[i * 4 + 0] = f2bf(x4.x); bb[i * 4 + 1] = f2bf(x4.y);
        bb[i * 4 + 2] = f2bf(x4.z); bb[i * 4 + 3] = f2bf(x4.w);
      }
#pragma unroll
      for (int d = 0; d < 3; ++d) {
        bf16x8 v;
#pragma unroll
        for (int j = 0; j < 8; ++j) v[j] = (short)bb[3 * j + d];
        a1[d][h] = v;
      }
    }
    {
      unsigned short bb[40];
#pragma unroll
      for (int i = 0; i < 10; ++i) {
        float4 x4 = fr4[80 + 10 * q + i];
        bb[i * 4 + 0] = f2bf(x4.x); bb[i * 4 + 1] = f2bf(x4.y);
        bb[i * 4 + 2] = f2bf(x4.z); bb[i * 4 + 3] = f2bf(x4.w);
      }
#pragma unroll
      for (int d = 0; d < 5; ++d) {
        bf16x8 v;
#pragma unroll
        for (int j = 0; j < 8; ++j) v[j] = (short)bb[5 * j + d];
        a2[d] = v;
      }
    }

    // x for logit dot, straight from global (L1 hit), clamped for tails
    auto xg = [&](int r, int c) -> float {
      int nn = nt + q * 4 + r;
      if (nn >= N) nn = N - 1;
      return f[(size_t)nn * 480 + c];
    };

    // ---- u-phase (slice) + dot, interleaved per irrep ----
    float pl[4] = {0.f, 0.f, 0.f, 0.f};
#pragma unroll
    for (int ctl = 0; ctl < 2; ++ctl) {
      f32x4 u = {0.f, 0.f, 0.f, 0.f};
      u = MFMA16(a0[0], Bu0[ctl][0], u);
      u = MFMA16(a0[1], Bu0[ctl][1], u);
      u = MFMA16(a0[2], Bu0[ctl][2], u);
      u = MFMA16(a0[3], Bu0[ctl][3], u);
      int c = (2 * w + ctl) * 16 + lm;
#pragma unroll
      for (int r = 0; r < 4; ++r) pl[r] += u[r] * xg(r, c);
    }
#pragma unroll
    for (int d = 0; d < 3; ++d) {
      f32x4 u = {0.f, 0.f, 0.f, 0.f};
      u = MFMA16(a1[d][0], Bu1[0], u);
      u = MFMA16(a1[d][1], Bu1[1], u);
      int c = 128 + 3 * (w * 16 + lm) + d;
#pragma unroll
      for (int r = 0; r < 4; ++r) pl[r] += u[r] * xg(r, c);
    }
    if (has2) {
#pragma unroll
      for (int d = 0; d < 5; ++d) {
        f32x4 u = {0.f, 0.f, 0.f, 0.f};
        u = MFMA16(a2[d], Bu2, u);
        int c = 320 + 5 * (ct2 * 16 + lm) + d;
#pragma unroll
        for (int r = 0; r < 4; ++r) pl[r] += u[r] * xg(r, c);
      }
    }
    // reduce slice partials across the 16-lane group, add to shared logits
#pragma unroll
    for (int off = 1; off < 16; off <<= 1) {
#pragma unroll
      for (int r = 0; r < 4; ++r) pl[r] += __shfl_xor(pl[r], off);
    }
    if (lm == 0) {
#pragma unroll
      for (int r = 0; r < 4; ++r) atomicAdd(&lds_logit[p][q * 4 + r], pl[r]);
    }
    __syncthreads();

    float wgt[4];
#pragma unroll
    for (int r = 0; r < 4; ++r) {
      int node = q * 4 + r;
      wgt[r] = (node < valid) ? __expf(lds_logit[p][node]) : 0.f;
    }
    // rotate: zero the buffer tile ti+2 will use (3-buffer schedule, race-free)
    if (t < 16) lds_logit[(ti + 2) % 3][t] = 0.f;

    // ---- segmented v accumulation over sorted batch ----
    {
      int nn = nt + (lm < valid ? lm : valid - 1);
      if (nn >= N) nn = N - 1;
      int gl = batch[nn];
      int gp = __shfl(gl, (lane == 0) ? 0 : lane - 1);
      unsigned long long bm = __ballot(lm > 0 && lm < valid && gl != gp);
      unsigned segm = (unsigned)bm & 0xFFFEu;

      int a = 0;
      while (a < valid) {
        unsigned hi = segm & ~((1u << (a + 1)) - 1u);
        int b = hi ? (int)__builtin_ctz(hi) : valid;
        int gs = __shfl(gl, a);
        if (gs != cur_g) {
          if (cur_g >= 0) flushf(cur_g);
          cur_g = gs;
        }
        int nq = q * 4;
        float m0 = (nq + 0 >= a && nq + 0 < b) ? wgt[0] : 0.f;
        float m1 = (nq + 1 >= a && nq + 1 < b) ? wgt[1] : 0.f;
        float m2 = (nq + 2 >= a && nq + 2 < b) ? wgt[2] : 0.f;
        float m3 = (nq + 3 >= a && nq + 3 < b) ? wgt[3] : 0.f;
        if (w == 0 && lm == 0) naccw += m0 + m1 + m2 + m3;
#pragma unroll
        for (int ctl = 0; ctl < 2; ++ctl) {
          f32x4 v = {0.f, 0.f, 0.f, 0.f};
          v = MFMA16(a0[0], Bv0[ctl][0], v);
          v = MFMA16(a0[1], Bv0[ctl][1], v);
          v = MFMA16(a0[2], Bv0[ctl][2], v);
          v = MFMA16(a0[3], Bv0[ctl][3], v);
          racc0[ctl] += m0 * v[0] + m1 * v[1] + m2 * v[2] + m3 * v[3];
        }
#pragma unroll
        for (int d = 0; d < 3; ++d) {
          f32x4 v = {0.f, 0.f, 0.f, 0.f};
          v = MFMA16(a1[d][0], Bv1[0], v);
          v = MFMA16(a1[d][1], Bv1[1], v);
          racc1[d] += m0 * v[0] + m1 * v[1] + m2 * v[2] + m3 * v[3];
        }
        if (has2) {
#pragma unroll
          for (int d = 0; d < 5; ++d) {
            f32x4 v = {0.f, 0.f, 0.f, 0.f};
            v = MFMA16(a2[d], Bv2, v);
            racc2[d] += m0 * v[0] + m1 * v[1] + m2 * v[2] + m3 * v[3];
          }
        }
        a = b;
      }
    }
  }
  if (cur_g >= 0) flushf(cur_g);
}

// ---------------------------------------------------------------------------
// finalize: out = num / max(norm, 1e-8)
// ---------------------------------------------------------------------------
__global__ __launch_bounds__(256) void finalize_kernel(
    float* __restrict__ out, const float* __restrict__ norm, int total) {
  int idx = blockIdx.x * blockDim.x + threadIdx.x;
  if (idx < total) {
    int g = idx / 480;
    out[idx] = out[idx] / fmaxf(norm[g], 1e-8f);
  }
}

extern "C" void kernel_launch(void* const* d_in, const int* in_sizes, int n_in,
                              void* d_out, int out_size, void* d_ws, size_t ws_size,
                              hipStream_t stream) {
  const float* f   = (const float*)d_in[0];
  const int* batch = (const int*)d_in[13];

  int N = in_sizes[0] / D_TOT;
  int G = out_size / D_TOT;

  // ws bytes: [0, 86016) Bpack bf16 (43008); [86016, ...) norm
  unsigned short* Bpack = (unsigned short*)d_ws;
  float* norm = (float*)((char*)d_ws + 86016);
  float* out  = (float*)d_out;

  hipMemsetAsync(d_out, 0, (size_t)out_size * sizeof(float), stream);
  hipMemsetAsync(norm, 0, (size_t)G * sizeof(float), stream);

  // one launch, 7 blocks; LDS sized for the M=128 instance (opt-in > 64 KB)
  int lds128 = (128 * 129 + 32 * 128) * 4;   // 82432
  hipFuncSetAttribute((const void*)precompute_all,
                      hipFuncAttributeMaxDynamicSharedMemorySize, lds128);
  precompute_all<<<7, 256, lds128, stream>>>(
      (const float*)d_in[1], (const float*)d_in[2], (const float*)d_in[3],
      (const float*)d_in[4], (const float*)d_in[5], (const float*)d_in[6],
      (const float*)d_in[10], (const float*)d_in[11], (const float*)d_in[12],
      (const float*)d_in[7], (const float*)d_in[8], (const float*)d_in[9],
      Bpack);

  int ntiles = (N + 15) / 16;
  int nblocks = 1024;                      // 4 blocks/CU at VGPR=128
  if (nblocks > ntiles) nblocks = ntiles;
  int tpb = (ntiles + nblocks - 1) / nblocks;

  fused_stat_kernel<<<nblocks, 256, 0, stream>>>(
      f, Bpack, batch, out, norm, N, tpb, ntiles);

  finalize_kernel<<<(G * D_TOT + 255) / 256, 256, 0, stream>>>(out, norm, G * D_TOT);
}